// Round 2
// baseline (1005.421 us; speedup 1.0000x reference)
//
#include <hip/hip_runtime.h>

#define HH 64
#define WW 64
#define S  68          // padded LDS row stride (floats)
#define PH 66          // padded rows (1-px zero frame)
#define NLQ 10
#define NR 8           // rows per thread (512 threads = 8 waves = 2/SIMD)

// One block per image (grid=256 = 1 block/CU). Thread t: column x=t&63, rows
// y0..y0+7.
//
// History: R2-R7 plateau at ~110us, VGPR_Count=108. Diagnosis: ~170 long-lived
// floats (Wt[90] + q0r[80]) get demoted to AGPRs; every USE pays a
// v_accvgpr_read VALU op. Wt is used 8x/step (720 reads) + q0r 1x (80) = ~800
// extra VALU/wave/step == the measured 2x gap over the 830-op useful stream.
// R8: LDS pad to trick the occupancy budget was DSE'd (dead store) - no-op.
//
// R9 fix (this version): make 108 arch VGPRs ENOUGH instead of fighting for 256.
//  - Wt never lives in registers: l-outer loop re-reads the current channel's
//    9 weights from LDS per step (3x ds_read_b128, uniform addr = broadcast,
//    co-issues with the other wave's VALU -> ~free). The per-step
//    __syncthreads() blocks LICM from re-hoisting them into 90 regs.
//  - q0r[80] pinned in AGPRs via explicit v_accvgpr_write/read asm: exactly
//    80 accvgpr_read/step (+10%), not 720. volatile reads block LICM.
// Hot-loop arch demand: 30 window + 12 weight + 8 m + misc ~= 65 << 108.
__global__ __launch_bounds__(512)
__attribute__((amdgpu_waves_per_eu(2, 2)))
void vin_fused(
    const float* __restrict__ X,    // [B,2,64,64]
    const float* __restrict__ Wh,   // [150,2,3,3]
    const float* __restrict__ bh,   // [150]
    const float* __restrict__ Wr,   // [150]
    const float* __restrict__ Wq,   // [10,1,3,3]
    const float* __restrict__ wtr,  // [10,1,3,3] transition
    const float* __restrict__ Wc,   // [4096]
    const float* __restrict__ bc,   // [1]
    float* __restrict__ out)        // [256 critic] ++ [256*40960 q]
{
  __shared__ float vb[2][PH * S];
  __shared__ float rb[PH * S];
  __shared__ float Wef[19];
  __shared__ float Wpart[152];
  __shared__ __align__(16) float Wts2[NLQ * 12];  // 9 weights + 3 pad per row
  __shared__ float Wqs[90];
  __shared__ float red[8];

  const int b  = blockIdx.x;
  const int t  = threadIdx.x;
  const int x  = t & 63;
  const int yg = t >> 6;
  const int y0 = yg * NR;
  const int base0 = y0 * S + x;   // top-left of 3x3 window for row y0 (padded)

  // q0 values, pinned in AGPRs. Written once, read once per step.
  float q0a[NR][NLQ];
#define Q0_WRITE(j, l, val) \
  asm("v_accvgpr_write_b32 %0, %1" : "=a"(q0a[j][l]) : "v"(val))
#define Q0_READ(dst, j, l) \
  asm volatile("v_accvgpr_read_b32 %0, %1" : "=v"(dst) : "a"(q0a[j][l]))

  // ---- zero LDS (frames must be 0; interiors overwritten) ----
  {
    float* vbf = &vb[0][0];
    for (int i = t; i < 2 * PH * S; i += 512) vbf[i] = 0.f;
    for (int i = t; i < PH * S; i += 512) rb[i] = 0.f;
  }
  __syncthreads();

  // ---- stage X into vb interiors; stage weights; collapse 150-ch conv ----
  const float* Xb = X + (size_t)b * (2 * HH * WW);
  for (int i = t; i < HH * WW; i += 512) {
    const int yy = i >> 6, xx = i & 63;
    vb[0][(yy + 1) * S + xx + 1] = Xb[i];
    vb[1][(yy + 1) * S + xx + 1] = Xb[HH * WW + i];
  }
  if (t < 152) {                       // parallel collapse: 19 outputs x 8 parts
    const int i = t >> 3, part = t & 7;
    float s = 0.f;
    if (i < 18) {
      for (int c = part; c < 150; c += 8) s += Wr[c] * Wh[c * 18 + i];
    } else {
      for (int c = part; c < 150; c += 8) s += Wr[c] * bh[c];
    }
    Wpart[t] = s;
  } else if (t >= 256 && t < 346) {
    const int i = t - 256;             // 0..89
    Wts2[(i / 9) * 12 + (i % 9)] = wtr[i];
  } else if (t >= 352 && t < 442) {
    Wqs[t - 352] = Wq[t - 352];
  }
  __syncthreads();
  if (t < 19) {
    float s = 0.f;
#pragma unroll
    for (int k = 0; k < 8; ++k) s += Wpart[t * 8 + k];
    Wef[t] = s;
  }
  __syncthreads();

  // ---- r = conv(X, Weff, pad=1) + beff -> rb ----
  {
    float We[19];
#pragma unroll
    for (int i = 0; i < 19; ++i) We[i] = Wef[i];
#pragma unroll
    for (int j = 0; j < NR; ++j) {
      const int tb = base0 + j * S;
      float s = We[18];
#pragma unroll
      for (int dy = 0; dy < 3; ++dy)
#pragma unroll
        for (int dx = 0; dx < 3; ++dx) {
          const int idx = tb + dy * S + dx;
          s = fmaf(vb[0][idx], We[dy * 3 + dx], s);
          s = fmaf(vb[1][idx], We[9 + dy * 3 + dx], s);
        }
      rb[tb + S + 1] = s;
    }
  }
  __syncthreads();

  // ---- q0 = conv(r, Wq, pad=1) -> AGPRs; v_init = max_l q0 -> vb[0] ----
  {
    float m[NR];
#pragma unroll
    for (int l = 0; l < NLQ; ++l) {
      const float w0 = Wqs[l * 9 + 0], w1 = Wqs[l * 9 + 1], w2 = Wqs[l * 9 + 2];
      const float w3 = Wqs[l * 9 + 3], w4 = Wqs[l * 9 + 4], w5 = Wqs[l * 9 + 5];
      const float w6 = Wqs[l * 9 + 6], w7 = Wqs[l * 9 + 7], w8 = Wqs[l * 9 + 8];
#pragma unroll
      for (int j = 0; j < NR; ++j) {
        const int a = base0 + j * S;
        float s;
        s = fmaf(w0, rb[a],             0.f);
        s = fmaf(w1, rb[a + 1],         s);
        s = fmaf(w2, rb[a + 2],         s);
        s = fmaf(w3, rb[a + S],         s);
        s = fmaf(w4, rb[a + S + 1],     s);
        s = fmaf(w5, rb[a + S + 2],     s);
        s = fmaf(w6, rb[a + 2 * S],     s);
        s = fmaf(w7, rb[a + 2 * S + 1], s);
        s = fmaf(w8, rb[a + 2 * S + 2], s);
        Q0_WRITE(j, l, s);
        m[j] = (l == 0) ? s : fmaxf(m[j], s);
      }
    }
#pragma unroll
    for (int j = 0; j < NR; ++j) vb[0][base0 + (j + 1) * S + 1] = m[j];
  }
  __syncthreads();

  // ---- K-loop: q = q0 + conv(v, w); v = max_ch(q) ----
  // l-outer: weights re-read from LDS per channel (broadcast, co-issued);
  // window rows held in 30 regs.
  auto step = [&](const float* __restrict__ vin, float* __restrict__ vout) {
    float win[NR + 2][3];
#pragma unroll
    for (int rr = 0; rr < NR + 2; ++rr) {
      const int a = base0 + rr * S;
      win[rr][0] = vin[a];
      win[rr][1] = vin[a + 1];
      win[rr][2] = vin[a + 2];
    }
    float m[NR];
#pragma unroll
    for (int l = 0; l < NLQ; ++l) {
      const float4* wr = (const float4*)&Wts2[l * 12];
      const float4 wA = wr[0], wB = wr[1], wC = wr[2];
#pragma unroll
      for (int j = 0; j < NR; ++j) {
        float s;
        Q0_READ(s, j, l);
        s = fmaf(wA.x, win[j][0],     s);
        s = fmaf(wA.y, win[j][1],     s);
        s = fmaf(wA.z, win[j][2],     s);
        s = fmaf(wA.w, win[j + 1][0], s);
        s = fmaf(wB.x, win[j + 1][1], s);
        s = fmaf(wB.y, win[j + 1][2], s);
        s = fmaf(wB.z, win[j + 2][0], s);
        s = fmaf(wB.w, win[j + 2][1], s);
        s = fmaf(wC.x, win[j + 2][2], s);
        m[j] = (l == 0) ? s : fmaxf(m[j], s);
      }
    }
#pragma unroll
    for (int j = 0; j < NR; ++j) vout[base0 + (j + 1) * S + 1] = m[j];
    __syncthreads();
  };

#pragma unroll 1
  for (int s2 = 0; s2 < 19; ++s2) { step(vb[0], vb[1]); step(vb[1], vb[0]); }
  step(vb[0], vb[1]);   // it = 38: reads vb[0], writes vb[1]

  // ---- final iteration (it=39): emit q + critic dot ----
  float wcv[NR];
#pragma unroll
  for (int j = 0; j < NR; ++j) wcv[j] = Wc[(y0 + j) * WW + x];

  float* qo = out + 256 + (size_t)b * (NLQ * HH * WW) + y0 * WW + x;
  float acc = 0.f;
  {
    const float* vin = vb[1];
    float win[NR + 2][3];
#pragma unroll
    for (int rr = 0; rr < NR + 2; ++rr) {
      const int a = base0 + rr * S;
      win[rr][0] = vin[a];
      win[rr][1] = vin[a + 1];
      win[rr][2] = vin[a + 2];
    }
    float m[NR];
#pragma unroll
    for (int l = 0; l < NLQ; ++l) {
      const float4* wr = (const float4*)&Wts2[l * 12];
      const float4 wA = wr[0], wB = wr[1], wC = wr[2];
#pragma unroll
      for (int j = 0; j < NR; ++j) {
        float s;
        Q0_READ(s, j, l);
        s = fmaf(wA.x, win[j][0],     s);
        s = fmaf(wA.y, win[j][1],     s);
        s = fmaf(wA.z, win[j][2],     s);
        s = fmaf(wA.w, win[j + 1][0], s);
        s = fmaf(wB.x, win[j + 1][1], s);
        s = fmaf(wB.y, win[j + 1][2], s);
        s = fmaf(wB.z, win[j + 2][0], s);
        s = fmaf(wB.w, win[j + 2][1], s);
        s = fmaf(wC.x, win[j + 2][2], s);
        qo[l * (HH * WW) + j * WW] = s;
        m[j] = (l == 0) ? s : fmaxf(m[j], s);
      }
    }
#pragma unroll
    for (int j = 0; j < NR; ++j) acc = fmaf(m[j], wcv[j], acc);
  }

  // ---- block-reduce critic ----
#pragma unroll
  for (int off = 32; off > 0; off >>= 1) acc += __shfl_down(acc, off);
  if (x == 0) red[yg] = acc;
  __syncthreads();
  if (t == 0) {
    float s = bc[0];
#pragma unroll
    for (int i = 0; i < 8; ++i) s += red[i];
    out[b] = s;
  }
}

extern "C" void kernel_launch(void* const* d_in, const int* in_sizes, int n_in,
                              void* d_out, int out_size, void* d_ws, size_t ws_size,
                              hipStream_t stream) {
  (void)n_in; (void)out_size; (void)d_ws; (void)ws_size;
  const float* X   = (const float*)d_in[0];
  const float* Wh  = (const float*)d_in[1];
  const float* bh  = (const float*)d_in[2];
  const float* Wr  = (const float*)d_in[3];
  const float* Wq  = (const float*)d_in[4];
  const float* wtr = (const float*)d_in[5];
  const float* Wc  = (const float*)d_in[6];
  const float* bc  = (const float*)d_in[7];
  float* out = (float*)d_out;

  const int B = in_sizes[0] / (2 * HH * WW);   // 256
  vin_fused<<<B, 512, 0, stream>>>(X, Wh, bh, Wr, Wq, wtr, Wc, bc, out);
}

// Round 3
// 180.418 us; speedup vs baseline: 5.5727x; 5.5727x over previous
//
#include <hip/hip_runtime.h>

#define HH 64
#define WW 64
#define S  68          // padded LDS row stride (floats)
#define PH 66          // padded rows (1-px zero frame)
#define NLQ 10
#define NR 8           // rows per thread (512 threads = 8 waves = 2/SIMD)

// One block per image (grid=256 = 1 block/CU). Thread t: column x=t&63, rows
// y0..y0+7.
//
// History:
//  R2-R7: ~110us plateau, VGPR_Count=108. Wt[90]+q0r[80] demoted to AGPRs;
//         Wt read 8x/step -> ~720 v_accvgpr_read/step = 2x VALU stream.
//  R8: LDS pad to trick the VGPR budget was DSE'd (dead store) - no-op.
//  R9: inline-asm "a"-constraint pinning of q0r -> compiler put the array in
//      SCRATCH (FETCH 4.4MB->814MB, WRITE 41->82MB, VALUBusy 14%, 940us).
//      Never hand-place AGPRs via asm on a C array.
//  R10 (this): q0r back to a plain local array (R1-style implicit demotion =
//      80 cheap accvgpr reads/step). The one real change vs R1: Wt NEVER
//      lives in registers - l-outer loop re-reads the current channel's 9
//      weights from LDS each step (3x ds_read_b128, uniform addr = broadcast,
//      issues in VALU gaps). Per-step __syncthreads() blocks LICM from
//      re-hoisting 90 weights into regs. Removes the 720 accvgpr reads.
__global__ __launch_bounds__(512)
__attribute__((amdgpu_waves_per_eu(2, 2)))
void vin_fused(
    const float* __restrict__ X,    // [B,2,64,64]
    const float* __restrict__ Wh,   // [150,2,3,3]
    const float* __restrict__ bh,   // [150]
    const float* __restrict__ Wr,   // [150]
    const float* __restrict__ Wq,   // [10,1,3,3]
    const float* __restrict__ wtr,  // [10,1,3,3] transition
    const float* __restrict__ Wc,   // [4096]
    const float* __restrict__ bc,   // [1]
    float* __restrict__ out)        // [256 critic] ++ [256*40960 q]
{
  __shared__ float vb[2][PH * S];
  __shared__ float rb[PH * S];
  __shared__ float Wef[19];
  __shared__ float Wpart[152];
  __shared__ __align__(16) float Wts2[NLQ * 12];  // 9 weights + 3 pad per row
  __shared__ float Wqs[90];
  __shared__ float red[8];

  const int b  = blockIdx.x;
  const int t  = threadIdx.x;
  const int x  = t & 63;
  const int yg = t >> 6;
  const int y0 = yg * NR;
  const int base0 = y0 * S + x;   // top-left of 3x3 window for row y0 (padded)

  // ---- zero LDS (frames must be 0; interiors overwritten) ----
  {
    float* vbf = &vb[0][0];
    for (int i = t; i < 2 * PH * S; i += 512) vbf[i] = 0.f;
    for (int i = t; i < PH * S; i += 512) rb[i] = 0.f;
  }
  __syncthreads();

  // ---- stage X into vb interiors; stage weights; collapse 150-ch conv ----
  const float* Xb = X + (size_t)b * (2 * HH * WW);
  for (int i = t; i < HH * WW; i += 512) {
    const int yy = i >> 6, xx = i & 63;
    vb[0][(yy + 1) * S + xx + 1] = Xb[i];
    vb[1][(yy + 1) * S + xx + 1] = Xb[HH * WW + i];
  }
  if (t < 152) {                       // parallel collapse: 19 outputs x 8 parts
    const int i = t >> 3, part = t & 7;
    float s = 0.f;
    if (i < 18) {
      for (int c = part; c < 150; c += 8) s += Wr[c] * Wh[c * 18 + i];
    } else {
      for (int c = part; c < 150; c += 8) s += Wr[c] * bh[c];
    }
    Wpart[t] = s;
  } else if (t >= 256 && t < 346) {
    const int i = t - 256;             // 0..89
    Wts2[(i / 9) * 12 + (i % 9)] = wtr[i];
  } else if (t >= 352 && t < 442) {
    Wqs[t - 352] = Wq[t - 352];
  }
  __syncthreads();
  if (t < 19) {
    float s = 0.f;
#pragma unroll
    for (int k = 0; k < 8; ++k) s += Wpart[t * 8 + k];
    Wef[t] = s;
  }
  __syncthreads();

  // ---- r = conv(X, Weff, pad=1) + beff -> rb ----
  {
    float We[19];
#pragma unroll
    for (int i = 0; i < 19; ++i) We[i] = Wef[i];
#pragma unroll
    for (int j = 0; j < NR; ++j) {
      const int tb = base0 + j * S;
      float s = We[18];
#pragma unroll
      for (int dy = 0; dy < 3; ++dy)
#pragma unroll
        for (int dx = 0; dx < 3; ++dx) {
          const int idx = tb + dy * S + dx;
          s = fmaf(vb[0][idx], We[dy * 3 + dx], s);
          s = fmaf(vb[1][idx], We[9 + dy * 3 + dx], s);
        }
      rb[tb + S + 1] = s;
    }
  }
  __syncthreads();

  // ---- q0 = conv(r, Wq, pad=1) -> q0r regs; v_init = max_l q0 -> vb[0] ----
  float q0r[NR][NLQ];
  {
    float m[NR];
#pragma unroll
    for (int l = 0; l < NLQ; ++l) {
      const float w0 = Wqs[l * 9 + 0], w1 = Wqs[l * 9 + 1], w2 = Wqs[l * 9 + 2];
      const float w3 = Wqs[l * 9 + 3], w4 = Wqs[l * 9 + 4], w5 = Wqs[l * 9 + 5];
      const float w6 = Wqs[l * 9 + 6], w7 = Wqs[l * 9 + 7], w8 = Wqs[l * 9 + 8];
#pragma unroll
      for (int j = 0; j < NR; ++j) {
        const int a = base0 + j * S;
        float s;
        s = fmaf(w0, rb[a],             0.f);
        s = fmaf(w1, rb[a + 1],         s);
        s = fmaf(w2, rb[a + 2],         s);
        s = fmaf(w3, rb[a + S],         s);
        s = fmaf(w4, rb[a + S + 1],     s);
        s = fmaf(w5, rb[a + S + 2],     s);
        s = fmaf(w6, rb[a + 2 * S],     s);
        s = fmaf(w7, rb[a + 2 * S + 1], s);
        s = fmaf(w8, rb[a + 2 * S + 2], s);
        q0r[j][l] = s;
        m[j] = (l == 0) ? s : fmaxf(m[j], s);
      }
    }
#pragma unroll
    for (int j = 0; j < NR; ++j) vb[0][base0 + (j + 1) * S + 1] = m[j];
  }
  __syncthreads();

  // ---- K-loop: q = q0 + conv(v, w); v = max_ch(q) ----
  // l-outer: weights re-read from LDS per channel (broadcast, co-issued);
  // window rows held in 30 regs.
  auto step = [&](const float* __restrict__ vin, float* __restrict__ vout) {
    float win[NR + 2][3];
#pragma unroll
    for (int rr = 0; rr < NR + 2; ++rr) {
      const int a = base0 + rr * S;
      win[rr][0] = vin[a];
      win[rr][1] = vin[a + 1];
      win[rr][2] = vin[a + 2];
    }
    float m[NR];
#pragma unroll
    for (int l = 0; l < NLQ; ++l) {
      const float4* wr = (const float4*)&Wts2[l * 12];
      const float4 wA = wr[0], wB = wr[1], wC = wr[2];
#pragma unroll
      for (int j = 0; j < NR; ++j) {
        float s = q0r[j][l];
        s = fmaf(wA.x, win[j][0],     s);
        s = fmaf(wA.y, win[j][1],     s);
        s = fmaf(wA.z, win[j][2],     s);
        s = fmaf(wA.w, win[j + 1][0], s);
        s = fmaf(wB.x, win[j + 1][1], s);
        s = fmaf(wB.y, win[j + 1][2], s);
        s = fmaf(wB.z, win[j + 2][0], s);
        s = fmaf(wB.w, win[j + 2][1], s);
        s = fmaf(wC.x, win[j + 2][2], s);
        m[j] = (l == 0) ? s : fmaxf(m[j], s);
      }
    }
#pragma unroll
    for (int j = 0; j < NR; ++j) vout[base0 + (j + 1) * S + 1] = m[j];
    __syncthreads();
  };

#pragma unroll 1
  for (int s2 = 0; s2 < 19; ++s2) { step(vb[0], vb[1]); step(vb[1], vb[0]); }
  step(vb[0], vb[1]);   // it = 38: reads vb[0], writes vb[1]

  // ---- final iteration (it=39): emit q + critic dot ----
  float wcv[NR];
#pragma unroll
  for (int j = 0; j < NR; ++j) wcv[j] = Wc[(y0 + j) * WW + x];

  float* qo = out + 256 + (size_t)b * (NLQ * HH * WW) + y0 * WW + x;
  float acc = 0.f;
  {
    const float* vin = vb[1];
    float win[NR + 2][3];
#pragma unroll
    for (int rr = 0; rr < NR + 2; ++rr) {
      const int a = base0 + rr * S;
      win[rr][0] = vin[a];
      win[rr][1] = vin[a + 1];
      win[rr][2] = vin[a + 2];
    }
    float m[NR];
#pragma unroll
    for (int l = 0; l < NLQ; ++l) {
      const float4* wr = (const float4*)&Wts2[l * 12];
      const float4 wA = wr[0], wB = wr[1], wC = wr[2];
#pragma unroll
      for (int j = 0; j < NR; ++j) {
        float s = q0r[j][l];
        s = fmaf(wA.x, win[j][0],     s);
        s = fmaf(wA.y, win[j][1],     s);
        s = fmaf(wA.z, win[j][2],     s);
        s = fmaf(wA.w, win[j + 1][0], s);
        s = fmaf(wB.x, win[j + 1][1], s);
        s = fmaf(wB.y, win[j + 1][2], s);
        s = fmaf(wB.z, win[j + 2][0], s);
        s = fmaf(wB.w, win[j + 2][1], s);
        s = fmaf(wC.x, win[j + 2][2], s);
        qo[l * (HH * WW) + j * WW] = s;
        m[j] = (l == 0) ? s : fmaxf(m[j], s);
      }
    }
#pragma unroll
    for (int j = 0; j < NR; ++j) acc = fmaf(m[j], wcv[j], acc);
  }

  // ---- block-reduce critic ----
#pragma unroll
  for (int off = 32; off > 0; off >>= 1) acc += __shfl_down(acc, off);
  if (x == 0) red[yg] = acc;
  __syncthreads();
  if (t == 0) {
    float s = bc[0];
#pragma unroll
    for (int i = 0; i < 8; ++i) s += red[i];
    out[b] = s;
  }
}

extern "C" void kernel_launch(void* const* d_in, const int* in_sizes, int n_in,
                              void* d_out, int out_size, void* d_ws, size_t ws_size,
                              hipStream_t stream) {
  (void)n_in; (void)out_size; (void)d_ws; (void)ws_size;
  const float* X   = (const float*)d_in[0];
  const float* Wh  = (const float*)d_in[1];
  const float* bh  = (const float*)d_in[2];
  const float* Wr  = (const float*)d_in[3];
  const float* Wq  = (const float*)d_in[4];
  const float* wtr = (const float*)d_in[5];
  const float* Wc  = (const float*)d_in[6];
  const float* bc  = (const float*)d_in[7];
  float* out = (float*)d_out;

  const int B = in_sizes[0] / (2 * HH * WW);   // 256
  vin_fused<<<B, 512, 0, stream>>>(X, Wh, bh, Wr, Wq, wtr, Wc, bc, out);
}